// Round 2
// baseline (367.477 us; speedup 1.0000x reference)
//
#include <hip/hip_runtime.h>
#include <math.h>

#define LN_EPS 1e-5f
#define NBLK 1024                     // must equal guaranteed-resident blocks (4/CU x 256 CU)

typedef __attribute__((ext_vector_type(8))) short bf16x8;
typedef __attribute__((ext_vector_type(4))) float f32x4;
typedef unsigned short ushort_t;
typedef unsigned int uint_t;

__device__ __forceinline__ ushort_t f2bf(float f) {
    uint_t u = __float_as_uint(f);
    u += 0x7FFF + ((u >> 16) & 1);          // RNE
    return (ushort_t)(u >> 16);
}

// 32 KB shared union — sized by the gemm reduction buffer.
union SMU {
    float red[2][64][64];                                     // gemm partials (32 KB)
    float tmat[32][33];                                       // prep transpose tile
    struct { float red8[8]; float stats[2]; } ln;             // layernorm
    struct { float part[4][36]; float sexp[36]; float inv_s; } agg;
};

// ---------------------------------------------------------------------------
// Grid barrier: monotonic counters, 16 arrival lines (128 B apart) + master.
// Arrival: agent-scope atomicAdd. Poll: agent-scope load (no RMW storm) with
// s_sleep. Bounded spin: degrades to wrong answer, never hangs the harness.
// __threadfence() = agent-scope fence (release before arrive / acquire after).
// Residency guaranteed by __launch_bounds__(256,4) + 32 KB LDS = 4 blocks/CU.
// ---------------------------------------------------------------------------
__device__ __forceinline__ void gbar(uint_t* cnt, int phase) {
    __syncthreads();
    if (threadIdx.x == 0) {
        __threadfence();
        uint_t* sub = cnt + (blockIdx.x & 15) * 32;
        uint_t* mst = cnt + 512;
        uint_t old = atomicAdd(sub, 1u);
        if (old == (uint_t)(phase * (NBLK / 16) - 1))
            atomicAdd(mst, 1u);
        int it = 0;
        while (__hip_atomic_load(mst, __ATOMIC_RELAXED, __HIP_MEMORY_SCOPE_AGENT)
               < (uint_t)(phase * 16)) {
            __builtin_amdgcn_s_sleep(4);
            if (++it > (1 << 20)) break;    // safety bound (~0.1 s)
        }
        __threadfence();
    }
    __syncthreads();
}

// ---------------------------------------------------------------------------
// 64x64 tile GEMM, 2x2 wave split (kw = K-half, nw = 32-col half). Fragments
// loaded directly from global (A[M][K], Bt[N][K] bf16, both K-contiguous);
// 16x16x32 layout: row = lane&15, k = (lane>>4)*8 + j. One 32 KB LDS
// reduction (sum over 2 K-halves) + bias/relu epilogue.
// ---------------------------------------------------------------------------
__device__ __forceinline__ void do_gemm(
    const ushort_t* __restrict__ A, const ushort_t* __restrict__ Bt,
    const float* __restrict__ bias, float* __restrict__ C, int K,
    int yy, int bx, int relu, float (&red)[2][64][64])
{
    const int tid  = threadIdx.x;
    const int wave = tid >> 6;
    const int lane = tid & 63;
    const int kw   = wave >> 1;
    const int nw   = wave & 1;
    const int q    = lane >> 4;
    const int mj   = lane & 15;
    const int brow = yy * 64;
    const int bcol = bx * 64;

    const ushort_t* Ab = A  + (size_t)(brow + mj) * K + kw * (K >> 1) + q * 8;
    const ushort_t* Bb = Bt + (size_t)(bcol + nw * 32 + mj) * K + kw * (K >> 1) + q * 8;
    const int ksteps = K >> 6;              // (K/2)/32 per wave

    f32x4 acc[4][2] = {};
    #pragma unroll 2
    for (int s = 0; s < ksteps; ++s) {
        bf16x8 af[4], bf[2];
        #pragma unroll
        for (int i = 0; i < 4; ++i)
            af[i] = *(const bf16x8*)(Ab + (size_t)i * 16 * K + s * 32);
        #pragma unroll
        for (int i = 0; i < 2; ++i)
            bf[i] = *(const bf16x8*)(Bb + (size_t)i * 16 * K + s * 32);
        #pragma unroll
        for (int mi = 0; mi < 4; ++mi)
            #pragma unroll
            for (int ni = 0; ni < 2; ++ni)
                acc[mi][ni] = __builtin_amdgcn_mfma_f32_16x16x32_bf16(
                    af[mi], bf[ni], acc[mi][ni], 0, 0, 0);
    }

    // partials -> LDS  (C/D layout: row = q*4+r, col = mj within each 16x16)
    #pragma unroll
    for (int mi = 0; mi < 4; ++mi)
        #pragma unroll
        for (int ni = 0; ni < 2; ++ni)
            #pragma unroll
            for (int r = 0; r < 4; ++r)
                red[kw][mi * 16 + q * 4 + r][nw * 32 + ni * 16 + mj] = acc[mi][ni][r];
    __syncthreads();

    #pragma unroll
    for (int g = 0; g < 4; ++g) {
        const int idx = g * 1024 + tid * 4;
        const int row = idx >> 6, col = idx & 63;
        float4 v0 = *(float4*)&red[0][row][col];
        float4 v1 = *(float4*)&red[1][row][col];
        float4 o;
        o.x = v0.x + v1.x; o.y = v0.y + v1.y;
        o.z = v0.z + v1.z; o.w = v0.w + v1.w;
        if (bias) {
            float4 bv = *(const float4*)&bias[bcol + col];
            o.x += bv.x; o.y += bv.y; o.z += bv.z; o.w += bv.w;
        }
        if (relu) {
            o.x = fmaxf(o.x, 0.f); o.y = fmaxf(o.y, 0.f);
            o.z = fmaxf(o.z, 0.f); o.w = fmaxf(o.w, 0.f);
        }
        *(float4*)&C[(size_t)(brow + row) * 512 + bcol + col] = o;
    }
}

// ---------------------------------------------------------------------------
// Entire pipeline, one launch. 1024 blocks x 256 threads, all co-resident:
// __launch_bounds__(256,4) caps VGPRs at 128 (=> 4 blocks/CU by regs),
// LDS 32 KB (=> 5 blocks/CU), waves 16/CU (<=32). Phases separated by gbar.
// ---------------------------------------------------------------------------
__global__ __launch_bounds__(256, 4) void mega_kernel(
    const float* __restrict__ text, const float* __restrict__ image,
    const float* __restrict__ W_text, const float* __restrict__ b_text,
    const float* __restrict__ g_text, const float* __restrict__ beta_text,
    const float* __restrict__ W_img, const float* __restrict__ b_img,
    const float* __restrict__ g_img, const float* __restrict__ beta_img,
    const float* __restrict__ W1, const float* __restrict__ b1,
    const float* __restrict__ W2, const float* __restrict__ b2,
    float* __restrict__ out_scores, float* __restrict__ out_agg,
    float* ta, float* ia, ushort_t* text_bf, ushort_t* image_bf,
    float* ht, float* hi,
    ushort_t* Wt_t, ushort_t* Wi_t, ushort_t* W1t_t, ushort_t* W1i_t,
    ushort_t* ta_bf, ushort_t* ia_bf, uint_t* cnt)
{
    __shared__ SMU sm;
    const int tid = threadIdx.x;
    const int bid = blockIdx.x;

    // ---- P1: activations fp32->bf16 + weight transpose-convert ----------
    for (int vb = bid; vb < 5760; vb += NBLK) {
        if (vb < 3840) {
            const int i4 = (vb * 256 + tid) * 4;
            const float* src; ushort_t* dst; int off;
            if (i4 < 1572864) { src = text;  dst = text_bf;  off = i4; }
            else              { src = image; dst = image_bf; off = i4 - 1572864; }
            float4 v = *(const float4*)(src + off);
            ushort4 o;
            o.x = f2bf(v.x); o.y = f2bf(v.y); o.z = f2bf(v.z); o.w = f2bf(v.w);
            *(ushort4*)(dst + off) = o;
        } else {
            int local = vb - 3840;
            const float* src; ushort_t* dst; int K;
            if      (local < 384)  { src = W_text;       dst = Wt_t;  K = 768;  }
            else if (local < 1408) { src = W_img;        dst = Wi_t;  K = 2048; local -= 384; }
            else if (local < 1664) { src = W1;           dst = W1t_t; K = 512;  local -= 1408; }
            else                   { src = W1 + 512*512; dst = W1i_t; K = 512;  local -= 1664; }
            const int ntk = K / 32;
            const int k0 = (local % ntk) * 32;
            const int n0 = (local / ntk) * 32;
            const int x = tid % 32, y = tid / 32;
            #pragma unroll
            for (int j = 0; j < 4; ++j)
                sm.tmat[y + 8 * j][x] = src[(size_t)(k0 + y + 8 * j) * 512 + n0 + x];
            __syncthreads();
            #pragma unroll
            for (int j = 0; j < 4; ++j)
                dst[(size_t)(n0 + y + 8 * j) * K + k0 + x] = f2bf(sm.tmat[x][y + 8 * j]);
            __syncthreads();                // tmat reuse across grid-stride iters
        }
    }
    gbar(cnt, 1);

    // ---- P2: both projections + bias + relu -----------------------------
    if (bid < 400) {
        const int t  = (bid & 7) * 50 + (bid >> 3);   // XCD-contiguous raster
        const int yy = t >> 3, x = t & 7;
        if (yy < 32) do_gemm(text_bf,  Wt_t, b_text, ta, 768,  yy,      x, 1, sm.red);
        else         do_gemm(image_bf, Wi_t, b_img,  ia, 2048, yy - 32, x, 1, sm.red);
    }
    gbar(cnt, 2);

    // ---- P3: both LayerNorms (text bf16-out; image bf16 + fp32 in-place) -
    for (int rr = bid; rr < 3200; rr += NBLK) {
        int row = rr;
        float* p; const float* g; const float* beta; ushort_t* obf; float* ofp;
        if (row < 2048) {
            p = ta + (size_t)row * 512; g = g_text; beta = beta_text;
            obf = ta_bf + (size_t)row * 512; ofp = nullptr;
        } else {
            row -= 2048;
            p = ia + (size_t)row * 512; g = g_img; beta = beta_img;
            obf = ia_bf + (size_t)row * 512; ofp = ia + (size_t)row * 512;
        }
        float2 v = *(const float2*)&p[tid * 2];
        float s  = v.x + v.y;
        float ss = v.x * v.x + v.y * v.y;
        #pragma unroll
        for (int off = 32; off; off >>= 1) {
            s  += __shfl_down(s, off);
            ss += __shfl_down(ss, off);
        }
        if ((tid & 63) == 0) {
            sm.ln.red8[(tid >> 6) * 2]     = s;
            sm.ln.red8[(tid >> 6) * 2 + 1] = ss;
        }
        __syncthreads();
        if (tid == 0) {
            float S  = sm.ln.red8[0] + sm.ln.red8[2] + sm.ln.red8[4] + sm.ln.red8[6];
            float SS = sm.ln.red8[1] + sm.ln.red8[3] + sm.ln.red8[5] + sm.ln.red8[7];
            float mu  = S * (1.f / 512.f);
            float var = SS * (1.f / 512.f) - mu * mu;
            sm.ln.stats[0] = mu;
            sm.ln.stats[1] = rsqrtf(var + LN_EPS);
        }
        __syncthreads();
        const float mu = sm.ln.stats[0], rstd = sm.ln.stats[1];
        float2 gv = *(const float2*)&g[tid * 2];
        float2 bv = *(const float2*)&beta[tid * 2];
        float o0 = (v.x - mu) * rstd * gv.x + bv.x;
        float o1 = (v.y - mu) * rstd * gv.y + bv.y;
        ushort2 ob; ob.x = f2bf(o0); ob.y = f2bf(o1);
        *(ushort2*)&obf[tid * 2] = ob;
        if (ofp) { float2 of; of.x = o0; of.y = o1; *(float2*)&ofp[tid * 2] = of; }
        __syncthreads();                    // sm.ln reuse across iterations
    }
    gbar(cnt, 3);

    // ---- P4: h_t (no bias) and h_i (+b1) ---------------------------------
    if (bid < 400) {
        const int t  = (bid & 7) * 50 + (bid >> 3);
        const int yy = t >> 3, x = t & 7;
        if (yy < 32) do_gemm(ta_bf, W1t_t, nullptr, ht, 512, yy,      x, 0, sm.red);
        else         do_gemm(ia_bf, W1i_t, b1,      hi, 512, yy - 32, x, 0, sm.red);
    }
    gbar(cnt, 4);

    // ---- P5: pair scores + sigmoid --------------------------------------
    {
        const int lane = tid & 63;
        const int wave = tid >> 6;
        float w2v[8];
        #pragma unroll
        for (int j = 0; j < 8; ++j) w2v[j] = W2[lane + 64 * j];
        const float bb = b2[0];
        const int sbe = ((bid & 7) << 7) + (bid >> 3);   // same-b blocks -> same XCD
        #pragma unroll
        for (int u = 0; u < 2; ++u) {
            const int be = sbe + u * 1024;
            const int b  = be >> 6;
            float htv[8];
            const float* htp = ht + (size_t)be * 512;
            #pragma unroll
            for (int j = 0; j < 8; ++j) htv[j] = htp[lane + 64 * j];
            const float* hib = hi + (size_t)b * 36 * 512;
            for (int r = wave; r < 36; r += 4) {
                const float* hir = hib + (size_t)r * 512;
                float acc = 0.f;
                #pragma unroll
                for (int j = 0; j < 8; ++j) {
                    float h = fmaxf(htv[j] + hir[lane + 64 * j], 0.f);
                    acc = fmaf(h, w2v[j], acc);
                }
                #pragma unroll
                for (int off = 32; off; off >>= 1) acc += __shfl_down(acc, off);
                if (lane == 0) {
                    float sr = acc + bb;
                    out_scores[(size_t)be * 36 + r] = 1.f / (1.f + expf(-sr));
                }
            }
        }
    }
    gbar(cnt, 5);

    // ---- P6: softmax + aggregation (64 units: 2 d-halves per batch) ------
    if (bid < 64) {
        const int b  = bid >> 1;
        const int d0 = (bid & 1) << 8;
        const float* sc = out_scores + (size_t)b * 2304;
        const int e4 = tid >> 6;
        const int r  = tid & 63;
        if (r < 36) {
            float p = 0.f;
            #pragma unroll
            for (int e = 0; e < 16; ++e) p += expf(sc[(e * 4 + e4) * 36 + r]);
            sm.agg.part[e4][r] = p;
        }
        __syncthreads();
        if (tid < 36)
            sm.agg.sexp[tid] = sm.agg.part[0][tid] + sm.agg.part[1][tid]
                             + sm.agg.part[2][tid] + sm.agg.part[3][tid];
        __syncthreads();
        if (tid < 64) {
            float v = (tid < 36) ? sm.agg.sexp[tid] : 0.f;
            #pragma unroll
            for (int off = 32; off; off >>= 1) v += __shfl_down(v, off);
            if (tid == 0) sm.agg.inv_s = 1.f / (v * 64.f);
        }
        __syncthreads();
        const float inv = sm.agg.inv_s;
        const float* ib = ia + (size_t)b * 36 * 512;
        const int d = d0 + tid;
        float acc = 0.f;
        #pragma unroll
        for (int rr2 = 0; rr2 < 36; ++rr2)
            acc = fmaf(sm.agg.sexp[rr2] * inv, ib[rr2 * 512 + d], acc);
        out_agg[(size_t)b * 512 + d] = acc;
    }
}

// ---------------------------------------------------------------------------
extern "C" void kernel_launch(void* const* d_in, const int* in_sizes, int n_in,
                              void* d_out, int out_size, void* d_ws, size_t ws_size,
                              hipStream_t stream)
{
    const float* text      = (const float*)d_in[0];
    const float* image     = (const float*)d_in[1];
    const float* W_text    = (const float*)d_in[2];
    const float* b_text    = (const float*)d_in[3];
    const float* g_text    = (const float*)d_in[4];
    const float* beta_text = (const float*)d_in[5];
    const float* W_img     = (const float*)d_in[6];
    const float* b_img     = (const float*)d_in[7];
    const float* g_img     = (const float*)d_in[8];
    const float* beta_img  = (const float*)d_in[9];
    const float* W1        = (const float*)d_in[10];
    const float* b1        = (const float*)d_in[11];
    const float* W2        = (const float*)d_in[12];
    const float* b2        = (const float*)d_in[13];

    float* out_scores = (float*)d_out;            // 32*64*36
    float* out_agg    = (float*)d_out + 73728;    // 32*512

    char* ws = (char*)d_ws;
    float*    ta       = (float*)(ws);                          // 4 MB
    float*    ia       = (float*)(ws + (4u << 20));             // 2.25 MB
    ushort_t* text_bf  = (ushort_t*)(ws + 6402048);             // 3 MB   } region X
    ushort_t* image_bf = (ushort_t*)(ws + 6402048 + 3145728);   // 4.5 MB } 7.5 MB
    float*    ht       = (float*)(ws + 6402048);                // 4 MB   (aliases X)
    float*    hi       = (float*)(ws + 6402048 + 4194304);      // 2.25 MB(aliases X)
    char*     wbase    = ws + 6402048 + 7864320;
    ushort_t* Wt_t     = (ushort_t*)(wbase);                    // 0.75 MB
    ushort_t* Wi_t     = (ushort_t*)(wbase + 786432);           // 2 MB
    ushort_t* W1t_t    = (ushort_t*)(wbase + 786432 + 2097152); // 0.5 MB
    ushort_t* W1i_t    = (ushort_t*)(wbase + 786432 + 2097152 + 524288);
    char*     bfbase   = wbase + 786432 + 2097152 + 2 * 524288;
    ushort_t* ta_bf    = (ushort_t*)(bfbase);                   // 2 MB
    ushort_t* ia_bf    = (ushort_t*)(bfbase + 2097152);         // 1.125 MB
    uint_t*   cnt      = (uint_t*)(ws + 25165824);              // barrier counters @24 MB

    (void)hipMemsetAsync(cnt, 0, 4096, stream);
    mega_kernel<<<NBLK, 256, 0, stream>>>(
        text, image, W_text, b_text, g_text, beta_text,
        W_img, b_img, g_img, beta_img, W1, b1, W2, b2,
        out_scores, out_agg,
        ta, ia, text_bf, image_bf, ht, hi,
        Wt_t, Wi_t, W1t_t, W1i_t, ta_bf, ia_bf, cnt);
}

// Round 3
// 154.119 us; speedup vs baseline: 2.3844x; 2.3844x over previous
//
#include <hip/hip_runtime.h>
#include <math.h>

#define LN_EPS 1e-5f

typedef __attribute__((ext_vector_type(8))) short bf16x8;
typedef __attribute__((ext_vector_type(4))) float f32x4;
typedef unsigned short ushort_t;
typedef unsigned int uint_t;

__device__ __forceinline__ ushort_t f2bf(float f) {
    uint_t u = __float_as_uint(f);
    u += 0x7FFF + ((u >> 16) & 1);          // RNE
    return (ushort_t)(u >> 16);
}

// ---------------------------------------------------------------------------
// Prep: [0,3840) activations fp32->bf16 (flat, 4/thr)
//       [3840,5760) transpose-convert weights [K][512]f32 -> [512][K]bf16,
//                   W1 halves scaled by LN gamma (g_text / g_img) per k-row.
//       5760: zero the stats buffer (3200 rows x {sum,sumsq}).
//       [5761,5769): folded-vector partials gW/bW = coef^T @ W1half,
//                    4 k-chunks x {text,img}, stored as [vec][4][512].
// ---------------------------------------------------------------------------
__global__ __launch_bounds__(256) void prep_kernel(
    const float* __restrict__ text, const float* __restrict__ image,
    ushort_t* __restrict__ text_bf, ushort_t* __restrict__ image_bf,
    const float* __restrict__ W_text, const float* __restrict__ W_img,
    const float* __restrict__ W1,
    const float* __restrict__ g_text, const float* __restrict__ beta_text,
    const float* __restrict__ g_img, const float* __restrict__ beta_img,
    ushort_t* __restrict__ Wt_t, ushort_t* __restrict__ Wi_t,
    ushort_t* __restrict__ W1t_g, ushort_t* __restrict__ W1i_g,
    float* __restrict__ stats, float* __restrict__ vparts)
{
    __shared__ float t[32][33];
    const int bid = blockIdx.x;
    const int tid = threadIdx.x;
    if (bid < 3840) {
        const int i4 = (bid * 256 + tid) * 4;
        const float* src; ushort_t* dst; int off;
        if (i4 < 1572864) { src = text;  dst = text_bf;  off = i4; }
        else              { src = image; dst = image_bf; off = i4 - 1572864; }
        float4 v = *(const float4*)(src + off);
        ushort4 o;
        o.x = f2bf(v.x); o.y = f2bf(v.y); o.z = f2bf(v.z); o.w = f2bf(v.w);
        *(ushort4*)(dst + off) = o;
        return;
    }
    int local = bid - 3840;
    if (local < 1920) {
        const float* src; ushort_t* dst; int K; const float* gs = nullptr;
        if      (local < 384)  { src = W_text;       dst = Wt_t;  K = 768;  }
        else if (local < 1408) { src = W_img;        dst = Wi_t;  K = 2048; local -= 384; }
        else if (local < 1664) { src = W1;           dst = W1t_g; K = 512;  local -= 1408; gs = g_text; }
        else                   { src = W1 + 512*512; dst = W1i_g; K = 512;  local -= 1664; gs = g_img; }
        const int ntk = K / 32;
        const int k0 = (local % ntk) * 32;
        const int n0 = (local / ntk) * 32;
        const int x = tid % 32, y = tid / 32;
        #pragma unroll
        for (int j = 0; j < 4; ++j)
            t[y + 8 * j][x] = src[(size_t)(k0 + y + 8 * j) * 512 + n0 + x];
        __syncthreads();
        const float gv = gs ? gs[k0 + x] : 1.f;
        #pragma unroll
        for (int j = 0; j < 4; ++j)
            dst[(size_t)(n0 + y + 8 * j) * K + k0 + x] = f2bf(t[x][y + 8 * j] * gv);
        return;
    }
    if (local == 1920) {                    // zero stats (6400 floats)
        for (int i = tid; i < 6400; i += 256) stats[i] = 0.f;
        return;
    }
    // folded-vector partial blocks: j in [0,8)
    {
        const int j    = local - 1921;
        const int half = j >> 2;            // 0 = text (W1[:512]), 1 = image
        const int jj   = j & 3;             // k-chunk of 128
        const float* cg = half ? g_img : g_text;
        const float* cb = half ? beta_img : beta_text;
        const float* Wb = W1 + (size_t)(half * 512 + jj * 128) * 512;
        const int n = tid;
        float ag0 = 0.f, ab0 = 0.f, ag1 = 0.f, ab1 = 0.f;
        #pragma unroll 4
        for (int k = 0; k < 128; ++k) {
            const float c1 = cg[jj * 128 + k];
            const float c2 = cb[jj * 128 + k];
            const float w0 = Wb[(size_t)k * 512 + n];
            const float w1 = Wb[(size_t)k * 512 + n + 256];
            ag0 = fmaf(c1, w0, ag0); ab0 = fmaf(c2, w0, ab0);
            ag1 = fmaf(c1, w1, ag1); ab1 = fmaf(c2, w1, ab1);
        }
        float* vg = vparts + (size_t)(half * 2 + 0) * 2048 + jj * 512;
        float* vb = vparts + (size_t)(half * 2 + 1) * 2048 + jj * 512;
        vg[n] = ag0; vg[n + 256] = ag1;
        vb[n] = ab0; vb[n + 256] = ab1;
    }
}

// ---------------------------------------------------------------------------
// GEMM core (identical to verified baseline): barrier-free split-K bf16 MFMA,
// C[64x64]/block, N=512. A[M][K], Bt[N][K] both K-contiguous bf16; fragments
// loaded directly from global (16x16x32 layout row=lane&15, k=(lane>>4)*8+j).
// 4 waves split K; one LDS reduction. Two problems per launch via blockIdx.y.
//
// gemm1 epilogue: +bias, relu, write bf16 (and fp32 if Cfp), and accumulate
// per-row {sum, sumsq} into stats via atomics (for the folded LayerNorm).
// ---------------------------------------------------------------------------
__device__ __forceinline__ void gemm_core(
    const ushort_t* __restrict__ A, const ushort_t* __restrict__ Bt, int K,
    int brow, int bcol, int wave, int lane, float (&red)[4][64][64])
{
    const int q  = lane >> 4;
    const int mj = lane & 15;
    const ushort_t* Ab = A  + (size_t)(brow + mj) * K + q * 8;
    const ushort_t* Bb = Bt + (size_t)(bcol + mj) * K + q * 8;
    const int kw0    = wave * (K >> 2);
    const int ksteps = K >> 7;

    f32x4 acc[4][4] = {};
    #pragma unroll 2
    for (int s = 0; s < ksteps; ++s) {
        const int k = kw0 + s * 32;
        bf16x8 af[4], bf[4];
        #pragma unroll
        for (int i = 0; i < 4; ++i) {
            af[i] = *(const bf16x8*)(Ab + (size_t)i * 16 * K + k);
            bf[i] = *(const bf16x8*)(Bb + (size_t)i * 16 * K + k);
        }
        #pragma unroll
        for (int mi = 0; mi < 4; ++mi)
            #pragma unroll
            for (int ni = 0; ni < 4; ++ni)
                acc[mi][ni] = __builtin_amdgcn_mfma_f32_16x16x32_bf16(
                    af[mi], bf[ni], acc[mi][ni], 0, 0, 0);
    }
    #pragma unroll
    for (int mi = 0; mi < 4; ++mi)
        #pragma unroll
        for (int ni = 0; ni < 4; ++ni)
            #pragma unroll
            for (int r = 0; r < 4; ++r)
                red[wave][mi * 16 + q * 4 + r][ni * 16 + mj] = acc[mi][ni][r];
    __syncthreads();
}

__global__ __launch_bounds__(256) void gemm1_kernel(
    const ushort_t* __restrict__ A0, const ushort_t* __restrict__ B0,
    const float* __restrict__ bias0, ushort_t* __restrict__ Cb0,
    float* __restrict__ Cf0, float* __restrict__ st0, int K0,
    const ushort_t* __restrict__ A1, const ushort_t* __restrict__ B1,
    const float* __restrict__ bias1, ushort_t* __restrict__ Cb1,
    float* __restrict__ Cf1, float* __restrict__ st1, int K1,
    int ysplit)
{
    __shared__ float red[4][64][64];
    const ushort_t* A; const ushort_t* Bt; const float* bias;
    ushort_t* Cb; float* Cf; float* st; int K;
    int yy = blockIdx.y;
    if (yy < ysplit) { A=A0; Bt=B0; bias=bias0; Cb=Cb0; Cf=Cf0; st=st0; K=K0; }
    else { A=A1; Bt=B1; bias=bias1; Cb=Cb1; Cf=Cf1; st=st1; K=K1; yy -= ysplit; }

    const int tid  = threadIdx.x;
    const int brow = yy * 64;
    const int bcol = blockIdx.x * 64;
    gemm_core(A, Bt, K, brow, bcol, tid >> 6, tid & 63, red);

    #pragma unroll
    for (int g = 0; g < 4; ++g) {
        const int idx = g * 1024 + tid * 4;
        const int row = idx >> 6, col = idx & 63;
        float4 v0 = *(float4*)&red[0][row][col];
        float4 v1 = *(float4*)&red[1][row][col];
        float4 v2 = *(float4*)&red[2][row][col];
        float4 v3 = *(float4*)&red[3][row][col];
        float4 o;
        o.x = (v0.x + v1.x) + (v2.x + v3.x);
        o.y = (v0.y + v1.y) + (v2.y + v3.y);
        o.z = (v0.z + v1.z) + (v2.z + v3.z);
        o.w = (v0.w + v1.w) + (v2.w + v3.w);
        float4 bv = *(const float4*)&bias[bcol + col];
        o.x = fmaxf(o.x + bv.x, 0.f); o.y = fmaxf(o.y + bv.y, 0.f);
        o.z = fmaxf(o.z + bv.z, 0.f); o.w = fmaxf(o.w + bv.w, 0.f);
        ushort4 ob;
        ob.x = f2bf(o.x); ob.y = f2bf(o.y); ob.z = f2bf(o.z); ob.w = f2bf(o.w);
        *(ushort4*)&Cb[(size_t)(brow + row) * 512 + bcol + col] = ob;
        if (Cf) *(float4*)&Cf[(size_t)(brow + row) * 512 + bcol + col] = o;
        // per-row stats partials (this block's 64 cols)
        float s1 = (o.x + o.y) + (o.z + o.w);
        float s2 = fmaf(o.x, o.x, fmaf(o.y, o.y, fmaf(o.z, o.z, o.w * o.w)));
        #pragma unroll
        for (int off = 8; off; off >>= 1) {
            s1 += __shfl_down(s1, off, 16);
            s2 += __shfl_down(s2, off, 16);
        }
        if ((tid & 15) == 0) {
            atomicAdd(&st[(size_t)(brow + row) * 2],     s1);
            atomicAdd(&st[(size_t)(brow + row) * 2 + 1], s2);
        }
    }
}

// gemm2: A is RAW relu'd bf16; epilogue applies folded LayerNorm:
//   h = rstd*acc - rstd*mu*gW[col] + bW[col] (+ b1 for image half)
__global__ __launch_bounds__(256) void gemm2_kernel(
    const ushort_t* __restrict__ A0, const ushort_t* __restrict__ B0,
    const float* __restrict__ bias0, float* __restrict__ C0,
    const float* __restrict__ st0, const float* __restrict__ gW0,
    const float* __restrict__ bW0, int K0,
    const ushort_t* __restrict__ A1, const ushort_t* __restrict__ B1,
    const float* __restrict__ bias1, float* __restrict__ C1,
    const float* __restrict__ st1, const float* __restrict__ gW1,
    const float* __restrict__ bW1, int K1,
    int ysplit)
{
    __shared__ float red[4][64][64];
    const ushort_t* A; const ushort_t* Bt; const float* bias; float* C;
    const float* st; const float* gW; const float* bW; int K;
    int yy = blockIdx.y;
    if (yy < ysplit) { A=A0; Bt=B0; bias=bias0; C=C0; st=st0; gW=gW0; bW=bW0; K=K0; }
    else { A=A1; Bt=B1; bias=bias1; C=C1; st=st1; gW=gW1; bW=bW1; K=K1; yy -= ysplit; }

    const int tid  = threadIdx.x;
    const int brow = yy * 64;
    const int bcol = blockIdx.x * 64;
    gemm_core(A, Bt, K, brow, bcol, tid >> 6, tid & 63, red);

    #pragma unroll
    for (int g = 0; g < 4; ++g) {
        const int idx = g * 1024 + tid * 4;
        const int row = idx >> 6, col = idx & 63;
        float4 v0 = *(float4*)&red[0][row][col];
        float4 v1 = *(float4*)&red[1][row][col];
        float4 v2 = *(float4*)&red[2][row][col];
        float4 v3 = *(float4*)&red[3][row][col];
        float4 s;
        s.x = (v0.x + v1.x) + (v2.x + v3.x);
        s.y = (v0.y + v1.y) + (v2.y + v3.y);
        s.z = (v0.z + v1.z) + (v2.z + v3.z);
        s.w = (v0.w + v1.w) + (v2.w + v3.w);
        const float st1v = st[(size_t)(brow + row) * 2];
        const float st2v = st[(size_t)(brow + row) * 2 + 1];
        const float mu   = st1v * (1.f / 512.f);
        const float var  = st2v * (1.f / 512.f) - mu * mu;
        const float rstd = rsqrtf(var + LN_EPS);
        const int c = bcol + col;
        float4 gw = *(const float4*)&gW[c];
        float4 bw = *(const float4*)&bW[c];
        #pragma unroll
        for (int j = 1; j < 4; ++j) {
            float4 gp = *(const float4*)&gW[j * 512 + c];
            float4 bp = *(const float4*)&bW[j * 512 + c];
            gw.x += gp.x; gw.y += gp.y; gw.z += gp.z; gw.w += gp.w;
            bw.x += bp.x; bw.y += bp.y; bw.z += bp.z; bw.w += bp.w;
        }
        const float rm = rstd * mu;
        float4 o;
        o.x = fmaf(rstd, s.x, fmaf(-rm, gw.x, bw.x));
        o.y = fmaf(rstd, s.y, fmaf(-rm, gw.y, bw.y));
        o.z = fmaf(rstd, s.z, fmaf(-rm, gw.z, bw.z));
        o.w = fmaf(rstd, s.w, fmaf(-rm, gw.w, bw.w));
        if (bias) {
            float4 bb = *(const float4*)&bias[c];
            o.x += bb.x; o.y += bb.y; o.z += bb.z; o.w += bb.w;
        }
        *(float4*)&C[(size_t)(brow + row) * 512 + c] = o;
    }
}

// ---------------------------------------------------------------------------
// scores[b,e,r] = sigmoid( sum_d relu(h_t[b,e,d] + h_i[b,r,d]) * W2[d] + b2 )
// ---------------------------------------------------------------------------
__global__ __launch_bounds__(256) void scores_kernel(
    const float* __restrict__ ht, const float* __restrict__ hi,
    const float* __restrict__ W2, const float* __restrict__ b2,
    float* __restrict__ scores)
{
    const int be   = blockIdx.x;
    const int b    = be >> 6;
    const int tid  = threadIdx.x;
    const int lane = tid & 63;
    const int wave = tid >> 6;

    float htv[8], w2v[8];
    const float* htp = ht + (size_t)be * 512;
    #pragma unroll
    for (int j = 0; j < 8; ++j) {
        htv[j] = htp[lane + 64 * j];
        w2v[j] = W2[lane + 64 * j];
    }
    const float bb = b2[0];
    const float* hib = hi + (size_t)b * 36 * 512;

    for (int r = wave; r < 36; r += 4) {
        const float* hir = hib + (size_t)r * 512;
        float acc = 0.f;
        #pragma unroll
        for (int j = 0; j < 8; ++j) {
            float h = fmaxf(htv[j] + hir[lane + 64 * j], 0.f);
            acc = fmaf(h, w2v[j], acc);
        }
        #pragma unroll
        for (int off = 32; off; off >>= 1) acc += __shfl_down(acc, off);
        if (lane == 0) {
            float sr = acc + bb;
            scores[(size_t)be * 36 + r] = 1.f / (1.f + expf(-sr));
        }
    }
}

// ---------------------------------------------------------------------------
// Softmax + aggregation with folded image LayerNorm:
//   out_d = g_d * (sum_r coef_r * x[r,d] - S1) + beta_d/64
//   coef_r = W_r * rstd_r,  S1 = sum_r coef_r * mu_r,  W_r = sexp_r * inv.
// ---------------------------------------------------------------------------
__global__ __launch_bounds__(256) void agg_kernel(
    const float* __restrict__ scores, const float* __restrict__ img,
    const float* __restrict__ stats, const float* __restrict__ g_img,
    const float* __restrict__ beta_img, float* __restrict__ outAgg)
{
    const int b   = blockIdx.x;
    const int tid = threadIdx.x;
    const float* sc = scores + (size_t)b * 2304;

    __shared__ float part[4][36];
    __shared__ float sexp[36];
    __shared__ float inv_s;
    __shared__ float coef[36], cmu[36];

    const int e4 = tid >> 6;
    const int r  = tid & 63;
    if (r < 36) {
        float p = 0.f;
        #pragma unroll
        for (int e = 0; e < 16; ++e) p += expf(sc[(e * 4 + e4) * 36 + r]);
        part[e4][r] = p;
    }
    __syncthreads();
    if (tid < 36) sexp[tid] = part[0][tid] + part[1][tid] + part[2][tid] + part[3][tid];
    __syncthreads();
    if (tid < 64) {
        float v = (tid < 36) ? sexp[tid] : 0.f;
        #pragma unroll
        for (int off = 32; off; off >>= 1) v += __shfl_down(v, off);
        if (tid == 0) inv_s = 1.f / (v * 64.f);
    }
    __syncthreads();
    const float inv = inv_s;
    if (tid < 36) {
        const float s1 = stats[(size_t)(b * 36 + tid) * 2];
        const float s2 = stats[(size_t)(b * 36 + tid) * 2 + 1];
        const float mu   = s1 * (1.f / 512.f);
        const float var  = s2 * (1.f / 512.f) - mu * mu;
        const float rstd = rsqrtf(var + LN_EPS);
        const float c = sexp[tid] * inv * rstd;
        coef[tid] = c;
        cmu[tid]  = c * mu;
    }
    __syncthreads();
    float S1 = 0.f;
    #pragma unroll
    for (int rr = 0; rr < 36; ++rr) S1 += cmu[rr];
    const float S0 = 1.f / 64.f;            // sum_r W_r (softmax sums to 1)

    const float* ib = img + (size_t)b * 36 * 512;
    for (int d = tid; d < 512; d += 256) {
        float acc = 0.f;
        #pragma unroll
        for (int rr = 0; rr < 36; ++rr)
            acc = fmaf(coef[rr], ib[rr * 512 + d], acc);
        outAgg[(size_t)b * 512 + d] = fmaf(g_img[d], acc - S1, beta_img[d] * S0);
    }
}

// ---------------------------------------------------------------------------
extern "C" void kernel_launch(void* const* d_in, const int* in_sizes, int n_in,
                              void* d_out, int out_size, void* d_ws, size_t ws_size,
                              hipStream_t stream)
{
    const float* text      = (const float*)d_in[0];
    const float* image     = (const float*)d_in[1];
    const float* W_text    = (const float*)d_in[2];
    const float* b_text    = (const float*)d_in[3];
    const float* g_text    = (const float*)d_in[4];
    const float* beta_text = (const float*)d_in[5];
    const float* W_img     = (const float*)d_in[6];
    const float* b_img     = (const float*)d_in[7];
    const float* g_img     = (const float*)d_in[8];
    const float* beta_img  = (const float*)d_in[9];
    const float* W1        = (const float*)d_in[10];
    const float* b1        = (const float*)d_in[11];
    const float* W2        = (const float*)d_in[12];
    const float* b2        = (const float*)d_in[13];

    float* out_scores = (float*)d_out;            // 32*64*36
    float* out_agg    = (float*)d_out + 73728;    // 32*512

    char* ws = (char*)d_ws;
    ushort_t* ta_bf    = (ushort_t*)(ws);                       // 2 MB   raw relu'd text proj (bf16)
    ushort_t* ia_bf    = (ushort_t*)(ws + 2097152);             // 1.125 MB raw relu'd image proj (bf16)
    float*    ia       = (float*)(ws + 3276800);                // 2.25 MB raw relu'd image proj (fp32)
    float*    ht       = (float*)(ws + 5636096);                // 4 MB
    float*    hi       = (float*)(ws + 9830400);                // 2.25 MB
    ushort_t* text_bf  = (ushort_t*)(ws + 12189696);            // 3 MB
    ushort_t* image_bf = (ushort_t*)(ws + 15335424);            // 4.5 MB
    ushort_t* Wt_t     = (ushort_t*)(ws + 20054016);            // 0.75 MB
    ushort_t* Wi_t     = (ushort_t*)(ws + 20840448);            // 2 MB
    ushort_t* W1t_g    = (ushort_t*)(ws + 22937600);            // 0.5 MB (gamma-scaled)
    ushort_t* W1i_g    = (ushort_t*)(ws + 23461888);            // 0.5 MB (gamma-scaled)
    float*    stats    = (float*)(ws + 23986176);               // 3200 x {sum,sumsq}
    float*    vparts   = (float*)(ws + 24011776);               // 4 vecs x 4 parts x 512

    // 1) convert + transpose(+gamma-fold) + stats-zero + folded vectors
    prep_kernel<<<5769, 256, 0, stream>>>(
        text, image, text_bf, image_bf, W_text, W_img, W1,
        g_text, beta_text, g_img, beta_img,
        Wt_t, Wi_t, W1t_g, W1i_g, stats, vparts);
    // 2) both projections + bias + relu -> raw bf16 (+fp32 image) + row stats
    gemm1_kernel<<<dim3(8, 50), 256, 0, stream>>>(
        text_bf, Wt_t, b_text, ta_bf, nullptr, stats, 768,
        image_bf, Wi_t, b_img, ia_bf, ia, stats + 4096, 2048,
        32);
    // 3) h_t / h_i on raw bf16 with folded-LN epilogue (+b1 for image)
    gemm2_kernel<<<dim3(8, 50), 256, 0, stream>>>(
        ta_bf, W1t_g, nullptr, ht, stats,        vparts,        vparts + 2048, 512,
        ia_bf, W1i_g, b1,      hi, stats + 4096, vparts + 4096, vparts + 6144, 512,
        32);
    // 4) pair scores + sigmoid -> out[0]
    scores_kernel<<<2048, 256, 0, stream>>>(ht, hi, W2, b2, out_scores);
    // 5) softmax + aggregation with folded image LN -> out[1]
    agg_kernel<<<32, 256, 0, stream>>>(out_scores, ia, stats + 4096,
                                       g_img, beta_img, out_agg);
}